// Round 4
// baseline (385.370 us; speedup 1.0000x reference)
//
#include <hip/hip_runtime.h>

// ---------------- problem constants ----------------
#define B_  128
#define N_  512
#define F_  128
#define L_  64
#define H_  128
#define C_  10

typedef short  bf8_t  __attribute__((ext_vector_type(8)));   // 8 x bf16 (MFMA A/B frag)
typedef float  f32x4  __attribute__((ext_vector_type(4)));   // MFMA C/D frag
typedef unsigned short us8 __attribute__((ext_vector_type(8)));
typedef unsigned short us4 __attribute__((ext_vector_type(4)));

// fp32 -> bf16 (RNE) as raw ushort
static __device__ __forceinline__ unsigned short f2bf(float x) {
    union { float f; unsigned u; } c; c.f = x;
    unsigned r = (c.u + 0x7fffu + ((c.u >> 16) & 1u)) >> 16;
    return (unsigned short)r;
}
static __device__ __forceinline__ float bf2f(unsigned short s) {
    union { unsigned u; float f; } c; c.u = ((unsigned)s) << 16;
    return c.f;
}
static __device__ __forceinline__ float elu(float x) { return x > 0.f ? x : expm1f(x); }

// ws layout (float units) — no zero-init required anywhere
#define OFF_DEGP   0          // 524288  deg partials [b][8][512] (every slot written by k1)
#define OFF_DEG    524288     // 65536   (written by k2 prologue)
#define OFF_HPP    589824     // 65536   hp partials [8][b][64] (every slot written by k6)
#define OFF_KLP    655360     // 512
#define OFF_MSEP   655872     // 1024
#define OFF_TMU    656896     // 65536
#define OFF_TLV    722432     // 65536
#define OFF_V      787968     // 65536
#define OFF_W      853504     // 65536
#define OFF_H1Q    919296     // h1 bf16: 4194304 ushort = 2097152 float slots
#define OFF_GBF    3016448    // 33554432 ushort = 16777216 float slots
#define OFF_UBFT   19793664   // 4194304 ushort = 2097152 float slots
#define OFF_WSTBF  21890816   // 8192 ushort = 4096 float slots

// ---------------- k1: g -> bf16 + per-chunk column-sum partials; block(0,0) also preps W_s^T ----------------
// grid (4, B_), 256 thr. chunk c covers rows [c*128, c*128+128); half-warp split.
__global__ __launch_bounds__(256) void k1_deg(const float* __restrict__ g,
                                              const float* __restrict__ Ws,
                                              float* __restrict__ deg_part,
                                              unsigned short* __restrict__ gbf,
                                              unsigned short* __restrict__ WsTbf) {
    const int c = blockIdx.x, b = blockIdx.y;
    if (c == 0 && b == 0) {
        // side job: W_s^T -> bf16 (8192 elems); k2 launches after k1 completes
        for (int i = threadIdx.x; i < F_ * L_; i += 256) {
            int l = i >> 7, f = i & 127;                 // dest [l][f]
            WsTbf[i] = f2bf(Ws[f * L_ + l]);
        }
    }
    const int half = threadIdx.x >> 7, lane = threadIdx.x & 127;
    const int j  = lane * 4;
    const int i0 = c * 128 + half * 64;
    const float*    gp = g   + ((size_t)b * N_ + i0) * N_ + j;
    unsigned short* gq = gbf + ((size_t)b * N_ + i0) * N_ + j;
    float4 acc = make_float4(0.f, 0.f, 0.f, 0.f);
    #pragma unroll 8
    for (int r = 0; r < 64; ++r) {
        float4 v = *reinterpret_cast<const float4*>(gp + (size_t)r * N_);
        acc.x += v.x; acc.y += v.y; acc.z += v.z; acc.w += v.w;
        us4 q; q[0] = f2bf(v.x); q[1] = f2bf(v.y); q[2] = f2bf(v.z); q[3] = f2bf(v.w);
        *reinterpret_cast<us4*>(gq + (size_t)r * N_) = q;
    }
    *reinterpret_cast<float4*>(deg_part + (size_t)(b * 8 + c * 2 + half) * N_ + j) = acc;
}

// ---------------- k2: finalize deg; u^T (bf16) = ((h @ W_s)/deg)^T via MFMA ----------------
__global__ __launch_bounds__(256) void k2_u(const float* __restrict__ h,
                                            const unsigned short* __restrict__ WsTbf,
                                            const float* __restrict__ deg_part,
                                            float* __restrict__ deg,
                                            unsigned short* __restrict__ ubfT) {
    __shared__ float tile[64 * 65];
    __shared__ float sdeg[64];
    const int b    = blockIdx.y;
    const int m0   = blockIdx.x * 64;
    const int tid  = threadIdx.x;
    const int wave = tid >> 6, lane = tid & 63;
    const int ml = lane & 15, q = lane >> 4;
    const int row0 = wave * 16;

    // finalize deg for this block's 64 rows (each row finalized exactly once device-wide)
    if (tid < 64) {
        int j = m0 + tid;
        float s = 0.f;
        #pragma unroll
        for (int k = 0; k < 8; ++k) s += deg_part[(size_t)(b * 8 + k) * N_ + j];
        sdeg[tid] = s;
        deg[b * N_ + j] = s;
    }

    const float* A = h + (size_t)(b * N_ + m0 + row0 + ml) * F_ + q * 8;
    const unsigned short* Bb = WsTbf + ml * F_ + q * 8;

    f32x4 acc[4] = {};
    #pragma unroll
    for (int kk = 0; kk < F_; kk += 32) {
        float4 a0 = *reinterpret_cast<const float4*>(A + kk);
        float4 a1 = *reinterpret_cast<const float4*>(A + kk + 4);
        union { unsigned short s[8]; bf8_t v; } av;
        av.s[0] = f2bf(a0.x); av.s[1] = f2bf(a0.y); av.s[2] = f2bf(a0.z); av.s[3] = f2bf(a0.w);
        av.s[4] = f2bf(a1.x); av.s[5] = f2bf(a1.y); av.s[6] = f2bf(a1.z); av.s[7] = f2bf(a1.w);
        #pragma unroll
        for (int i = 0; i < 4; ++i) {
            bf8_t bv = *reinterpret_cast<const bf8_t*>(Bb + i * 16 * F_ + kk);
            acc[i] = __builtin_amdgcn_mfma_f32_16x16x32_bf16(av.v, bv, acc[i], 0, 0, 0);
        }
    }
    __syncthreads();   // sdeg ready; tile not yet written
    #pragma unroll
    for (int i = 0; i < 4; ++i) {
        int col = i * 16 + ml;
        #pragma unroll
        for (int r = 0; r < 4; ++r) {
            int rl = row0 + 4 * q + r;
            tile[rl * 65 + col] = acc[i][r] / sdeg[rl];
        }
    }
    __syncthreads();
    for (int jj = 0; jj < 16; ++jj) {
        int ll = wave + jj * 4;
        ubfT[(size_t)(b * L_ + ll) * N_ + m0 + lane] = f2bf(tile[lane * 65 + ll]);
    }
}

// ---------------- k3: h1 = ELU(g@u + b_s) via MFMA; fused tmu/tlv = (h1@Wmu|lv)/deg ----------------
__global__ __launch_bounds__(256) void k3_h1(const unsigned short* __restrict__ gbf,
                                             const unsigned short* __restrict__ ubfT,
                                             const float* __restrict__ b_s,
                                             const float* __restrict__ Wmu,
                                             const float* __restrict__ Wlv,
                                             const float* __restrict__ deg,
                                             unsigned short* __restrict__ h1q,
                                             float* __restrict__ tmu, float* __restrict__ tlv) {
    const int b    = blockIdx.y;
    const int tid  = threadIdx.x;
    const int wave = tid >> 6, lane = tid & 63;
    const int row0 = blockIdx.x * 64 + wave * 16;
    const int ml = lane & 15, q = lane >> 4;

    const unsigned short* A  = gbf  + (size_t)(b * N_ + row0 + ml) * N_ + q * 8;
    const unsigned short* B0 = ubfT + (size_t)(b * L_ + ml) * N_ + q * 8;

    f32x4 acc[4] = {};
    #pragma unroll 2
    for (int k = 0; k < N_; k += 32) {
        bf8_t a = *reinterpret_cast<const bf8_t*>(A + k);
        #pragma unroll
        for (int i = 0; i < 4; ++i) {
            bf8_t bb = *reinterpret_cast<const bf8_t*>(B0 + (size_t)i * 16 * N_ + k);
            acc[i] = __builtin_amdgcn_mfma_f32_16x16x32_bf16(a, bb, acc[i], 0, 0, 0);
        }
    }
    float bsv[4], wm[4], wl[4];
    #pragma unroll
    for (int i = 0; i < 4; ++i) {
        int col = i * 16 + ml;
        bsv[i] = b_s[col]; wm[i] = Wmu[col]; wl[i] = Wlv[col];
    }
    #pragma unroll
    for (int r = 0; r < 4; ++r) {
        int row = row0 + 4 * q + r;
        float pm = 0.f, pl = 0.f;
        #pragma unroll
        for (int i = 0; i < 4; ++i) {
            float hv = elu(acc[i][r] + bsv[i]);
            h1q[(size_t)(b * N_ + row) * L_ + i * 16 + ml] = f2bf(hv);
            pm = fmaf(hv, wm[i], pm);
            pl = fmaf(hv, wl[i], pl);
        }
        #pragma unroll
        for (int o = 1; o < 16; o <<= 1) { pm += __shfl_xor(pm, o); pl += __shfl_xor(pl, o); }
        if (ml == 0) {
            float idg = 1.f / deg[b * N_ + row];
            tmu[b * N_ + row] = pm * idg;
            tlv[b * N_ + row] = pl * idg;
        }
    }
}

// ---------------- k5: mu/lv -> z -> v, w = v/deg; per-block KL partial ----------------
__global__ __launch_bounds__(256) void k5_v(const unsigned short* __restrict__ gbf,
                                            const float* __restrict__ tmu, const float* __restrict__ tlv,
                                            const float* __restrict__ eps, const float* __restrict__ deg,
                                            const float* __restrict__ bmu, const float* __restrict__ blv,
                                            const float* __restrict__ beta,
                                            float* __restrict__ v, float* __restrict__ w,
                                            float* __restrict__ kl_part) {
    __shared__ float kls[4];
    const int b = blockIdx.y;
    const int wave = threadIdx.x >> 6, lane = threadIdx.x & 63;
    const int n0 = (blockIdx.x * 4 + wave) * 32;

    const float* tmr = tmu + b * N_ + lane * 8;
    const float* tlr = tlv + b * N_ + lane * 8;
    float tm[8], tl[8];
    *reinterpret_cast<float4*>(tm)     = *reinterpret_cast<const float4*>(tmr);
    *reinterpret_cast<float4*>(tm + 4) = *reinterpret_cast<const float4*>(tmr + 4);
    *reinterpret_cast<float4*>(tl)     = *reinterpret_cast<const float4*>(tlr);
    *reinterpret_cast<float4*>(tl + 4) = *reinterpret_cast<const float4*>(tlr + 4);

    const unsigned short* gbase = gbf + (size_t)(b * N_ + n0) * N_ + lane * 8;
    float myamu = 0.f, myalv = 0.f;
    #pragma unroll 4
    for (int r = 0; r < 32; ++r) {
        us8 gv = *reinterpret_cast<const us8*>(gbase + (size_t)r * N_);
        float amu = 0.f, alv = 0.f;
        #pragma unroll
        for (int j = 0; j < 8; ++j) {
            float gf = bf2f(gv[j]);
            amu = fmaf(gf, tm[j], amu);
            alv = fmaf(gf, tl[j], alv);
        }
        #pragma unroll
        for (int o = 32; o; o >>= 1) { amu += __shfl_xor(amu, o); alv += __shfl_xor(alv, o); }
        if (lane == r) { myamu = amu; myalv = alv; }
    }
    float klv = 0.f;
    if (lane < 32) {
        int n = n0 + lane;
        float mu = elu(myamu + bmu[0]);
        float lv = elu(myalv + blv[0]);
        float z  = mu + eps[b * N_ + n] * expf(0.5f * lv);
        float vv = 1.f / (1.f + expf(-beta[0] * z));
        v[b * N_ + n] = vv;
        w[b * N_ + n] = vv / deg[b * N_ + n];
        float e = expf(lv);
        klv = 1.f + 2.f * lv - mu * mu - e * e;
    }
    #pragma unroll
    for (int o = 32; o; o >>= 1) klv += __shfl_xor(klv, o);
    if (lane == 0) kls[wave] = klv;
    __syncthreads();
    if (threadIdx.x == 0)
        kl_part[blockIdx.y * 4 + blockIdx.x] = kls[0] + kls[1] + kls[2] + kls[3];
}

// ---------------- k6: p = g@w ; d = ELU(p*W_dec+b_dec); mse partial; hp partial ----------------
__global__ __launch_bounds__(256) void k6_dec(const unsigned short* __restrict__ gbf,
                                              const float* __restrict__ w, const float* __restrict__ v,
                                              const unsigned short* __restrict__ h1q,
                                              const float* __restrict__ Wdec, const float* __restrict__ bdec,
                                              float* __restrict__ hp_part, float* __restrict__ mse_part) {
    __shared__ float hps[4 * 64];
    __shared__ float mses[4];
    const int b = blockIdx.y;
    const int n0 = blockIdx.x * 64;
    const int tid = threadIdx.x, wave = tid >> 6, lane = tid & 63;
    const float wd = Wdec[lane], bd = bdec[lane];

    const float* wrow = w + b * N_ + lane * 8;
    float wr[8];
    *reinterpret_cast<float4*>(wr)     = *reinterpret_cast<const float4*>(wrow);
    *reinterpret_cast<float4*>(wr + 4) = *reinterpret_cast<const float4*>(wrow + 4);

    const unsigned short* gbase = gbf + (size_t)(b * N_ + n0 + wave * 16) * N_ + lane * 8;
    float hpl = 0.f, msep = 0.f;
    #pragma unroll 2
    for (int t = 0; t < 16; ++t) {
        int n = n0 + wave * 16 + t;
        us8 gv = *reinterpret_cast<const us8*>(gbase + (size_t)t * N_);
        float p = 0.f;
        #pragma unroll
        for (int j = 0; j < 8; ++j) p = fmaf(bf2f(gv[j]), wr[j], p);
        #pragma unroll
        for (int o = 32; o; o >>= 1) p += __shfl_xor(p, o);
        float dv = elu(p * wd + bd);
        float h1v = bf2f(h1q[(size_t)(b * N_ + n) * L_ + lane]);
        float diff = h1v - dv;
        msep = fmaf(diff, diff, msep);
        hpl  = fmaf(h1v, v[b * N_ + n], hpl);
    }
    hps[wave * 64 + lane] = hpl;
    #pragma unroll
    for (int o = 32; o; o >>= 1) msep += __shfl_xor(msep, o);
    if (lane == 0) mses[wave] = msep;
    __syncthreads();
    if (tid < 64) {
        float s = hps[tid] + hps[64 + tid] + hps[128 + tid] + hps[192 + tid];
        hp_part[(size_t)blockIdx.x * (B_ * 64) + b * 64 + tid] = s;
    }
    if (tid == 0)
        mse_part[blockIdx.y * 8 + blockIdx.x] = mses[0] + mses[1] + mses[2] + mses[3];
}

// ---------------- k7: merged classifier head + final loss (single block, 1024 thr) ----------------
__global__ __launch_bounds__(1024) void k7_final(const float* __restrict__ hp_part,
                                                 const float* __restrict__ W1, const float* __restrict__ b1,
                                                 const float* __restrict__ W2, const float* __restrict__ b2,
                                                 const int* __restrict__ labels,
                                                 const float* __restrict__ kl_part,
                                                 const float* __restrict__ mse_part,
                                                 float* __restrict__ out) {
    __shared__ float hpsh[B_ * 64];      // 32 KB
    __shared__ float acts[B_ * H_];      // 64 KB
    __shared__ float r1[128], r2[128], r3[128], r4[128];
    const int tid = threadIdx.x;

    // stage A: finalize hp = sum of 8 partials
    for (int idx = tid; idx < B_ * 64; idx += 1024) {
        float s = 0.f;
        #pragma unroll
        for (int x = 0; x < 8; ++x) s += hp_part[(size_t)x * (B_ * 64) + idx];
        hpsh[idx] = s;
    }
    __syncthreads();

    // stage B: layer1 acts = ELU(hp @ W1 + b1), 16384 outputs
    for (int o = tid; o < B_ * H_; o += 1024) {
        int b = o >> 7, hh = o & 127;
        float s = b1[hh];
        const float* hb = hpsh + b * 64;
        #pragma unroll 8
        for (int l = 0; l < 64; ++l) s = fmaf(hb[l], W1[l * H_ + hh], s);
        acts[o] = elu(s);
    }
    __syncthreads();

    // stage C: per-batch logits + log-softmax (threads 0..127); kl/mse gather (128..255)
    if (tid < B_) {
        float lg[C_];
        #pragma unroll
        for (int c = 0; c < C_; ++c) lg[c] = b2[c];
        const float* ab = acts + tid * H_;
        for (int hh = 0; hh < H_; ++hh) {
            float a = ab[hh];
            #pragma unroll
            for (int c = 0; c < C_; ++c) lg[c] = fmaf(a, W2[hh * C_ + c], lg[c]);
        }
        float mx = lg[0]; int am = 0;
        #pragma unroll
        for (int c = 1; c < C_; ++c) if (lg[c] > mx) { mx = lg[c]; am = c; }
        float se = 0.f;
        #pragma unroll
        for (int c = 0; c < C_; ++c) se += expf(lg[c] - mx);
        int lbl = labels[tid];
        r1[tid] = lg[lbl] - mx - logf(se);
        r2[tid] = (am == lbl) ? 1.f : 0.f;
    } else if (tid < 2 * B_) {
        int t = tid - B_;
        float k = 0.f, m = 0.f;
        #pragma unroll
        for (int i = 0; i < 4; ++i) k += kl_part[t * 4 + i];
        #pragma unroll
        for (int i = 0; i < 8; ++i) m += mse_part[t * 8 + i];
        r3[t] = k; r4[t] = m;
    }
    __syncthreads();
    for (int o = 64; o; o >>= 1) {
        if (tid < o) { r1[tid] += r1[tid + o]; r2[tid] += r2[tid + o];
                       r3[tid] += r3[tid + o]; r4[tid] += r4[tid + o]; }
        __syncthreads();
    }
    if (tid == 0) {
        float nll = -r1[0] / (float)B_;
        float kl  = r3[0] * (-0.5f / (65536.f * 65536.f));   // (-0.5/M)*(sum/M), M = B*N
        float mse = r4[0] / (float)(B_ * N_ * L_);
        out[0] = nll + kl + mse;
        out[1] = r2[0] / (float)B_;
    }
}

extern "C" void kernel_launch(void* const* d_in, const int* in_sizes, int n_in,
                              void* d_out, int out_size, void* d_ws, size_t ws_size,
                              hipStream_t stream) {
    const float* g     = (const float*)d_in[0];
    const float* h     = (const float*)d_in[1];
    const int*   labels= (const int*)  d_in[2];
    const float* eps   = (const float*)d_in[3];
    const float* W_s   = (const float*)d_in[4];
    const float* b_s   = (const float*)d_in[5];
    const float* W_mu  = (const float*)d_in[6];
    const float* b_mu  = (const float*)d_in[7];
    const float* W_lv  = (const float*)d_in[8];
    const float* b_lv  = (const float*)d_in[9];
    const float* W_dec = (const float*)d_in[10];
    const float* b_dec = (const float*)d_in[11];
    const float* W1    = (const float*)d_in[12];
    const float* b1    = (const float*)d_in[13];
    const float* W2    = (const float*)d_in[14];
    const float* b2    = (const float*)d_in[15];
    const float* beta  = (const float*)d_in[16];

    float* ws = (float*)d_ws;
    float* deg_part = ws + OFF_DEGP;
    float* deg      = ws + OFF_DEG;
    float* hp_part  = ws + OFF_HPP;
    float* kl_part  = ws + OFF_KLP;
    float* mse_part = ws + OFF_MSEP;
    float* tmu      = ws + OFF_TMU;
    float* tlv      = ws + OFF_TLV;
    float* vv       = ws + OFF_V;
    float* wv       = ws + OFF_W;
    unsigned short* h1q   = (unsigned short*)(ws + OFF_H1Q);
    unsigned short* gbf   = (unsigned short*)(ws + OFF_GBF);
    unsigned short* ubfT  = (unsigned short*)(ws + OFF_UBFT);
    unsigned short* WsTbf = (unsigned short*)(ws + OFF_WSTBF);

    k1_deg  <<<dim3(4, B_), 256, 0, stream>>>(g, W_s, deg_part, gbf, WsTbf);
    k2_u    <<<dim3(8, B_), 256, 0, stream>>>(h, WsTbf, deg_part, deg, ubfT);
    k3_h1   <<<dim3(8, B_), 256, 0, stream>>>(gbf, ubfT, b_s, W_mu, W_lv, deg, h1q, tmu, tlv);
    k5_v    <<<dim3(4, B_), 256, 0, stream>>>(gbf, tmu, tlv, eps, deg, b_mu, b_lv, beta, vv, wv, kl_part);
    k6_dec  <<<dim3(8, B_), 256, 0, stream>>>(gbf, wv, vv, h1q, W_dec, b_dec, hp_part, mse_part);
    k7_final<<<1, 1024, 0, stream>>>(hp_part, W1, b1, W2, b2, labels, kl_part, mse_part, (float*)d_out);
}

// Round 5
// 340.210 us; speedup vs baseline: 1.1327x; 1.1327x over previous
//
#include <hip/hip_runtime.h>

// ---------------- problem constants ----------------
#define B_  128
#define N_  512
#define F_  128
#define L_  64
#define H_  128
#define C_  10

typedef short  bf8_t  __attribute__((ext_vector_type(8)));   // 8 x bf16 (MFMA A/B frag)
typedef float  f32x4  __attribute__((ext_vector_type(4)));   // MFMA C/D frag
typedef unsigned short us8 __attribute__((ext_vector_type(8)));
typedef unsigned short us4 __attribute__((ext_vector_type(4)));

// fp32 -> bf16 (RNE) as raw ushort
static __device__ __forceinline__ unsigned short f2bf(float x) {
    union { float f; unsigned u; } c; c.f = x;
    unsigned r = (c.u + 0x7fffu + ((c.u >> 16) & 1u)) >> 16;
    return (unsigned short)r;
}
static __device__ __forceinline__ float bf2f(unsigned short s) {
    union { unsigned u; float f; } c; c.u = ((unsigned)s) << 16;
    return c.f;
}
static __device__ __forceinline__ float elu(float x) { return x > 0.f ? x : expm1f(x); }

// ws layout (float units) — no zero-init required anywhere
#define OFF_DEGP   0          // 524288  deg partials [b][8][512] (every slot written by k1)
#define OFF_DEG    524288     // 65536   (written by k2 prologue)
#define OFF_HPP    589824     // 65536   hp partials [8][b][64] (every slot written by k6)
#define OFF_KLP    655360     // 512
#define OFF_MSEP   655872     // 1024
#define OFF_TMU    656896     // 65536
#define OFF_TLV    722432     // 65536
#define OFF_V      787968     // 65536
#define OFF_W      853504     // 65536
#define OFF_LP     919040     // 128
#define OFF_COR    919168     // 128
#define OFF_H1Q    919296     // h1 bf16: 4194304 ushort = 2097152 float slots
#define OFF_GBF    3016448    // 33554432 ushort = 16777216 float slots
#define OFF_UBFT   19793664   // 4194304 ushort = 2097152 float slots
#define OFF_WSTBF  21890816   // 8192 ushort = 4096 float slots

// ---------------- k1: g -> bf16 + per-chunk column-sum partials; block(0,0) also preps W_s^T ----------------
// grid (4, B_), 256 thr. chunk c covers rows [c*128, c*128+128); half-warp split.
__global__ __launch_bounds__(256) void k1_deg(const float* __restrict__ g,
                                              const float* __restrict__ Ws,
                                              float* __restrict__ deg_part,
                                              unsigned short* __restrict__ gbf,
                                              unsigned short* __restrict__ WsTbf) {
    const int c = blockIdx.x, b = blockIdx.y;
    if (c == 0 && b == 0) {
        // side job: W_s^T -> bf16 (8192 elems); k2 launches after k1 completes
        for (int i = threadIdx.x; i < F_ * L_; i += 256) {
            int l = i >> 7, f = i & 127;                 // dest [l][f]
            WsTbf[i] = f2bf(Ws[f * L_ + l]);
        }
    }
    const int half = threadIdx.x >> 7, lane = threadIdx.x & 127;
    const int j  = lane * 4;
    const int i0 = c * 128 + half * 64;
    const float*    gp = g   + ((size_t)b * N_ + i0) * N_ + j;
    unsigned short* gq = gbf + ((size_t)b * N_ + i0) * N_ + j;
    float4 acc = make_float4(0.f, 0.f, 0.f, 0.f);
    #pragma unroll 8
    for (int r = 0; r < 64; ++r) {
        float4 v = *reinterpret_cast<const float4*>(gp + (size_t)r * N_);
        acc.x += v.x; acc.y += v.y; acc.z += v.z; acc.w += v.w;
        us4 q; q[0] = f2bf(v.x); q[1] = f2bf(v.y); q[2] = f2bf(v.z); q[3] = f2bf(v.w);
        *reinterpret_cast<us4*>(gq + (size_t)r * N_) = q;
    }
    *reinterpret_cast<float4*>(deg_part + (size_t)(b * 8 + c * 2 + half) * N_ + j) = acc;
}

// ---------------- k2: finalize deg; u^T (bf16) = ((h @ W_s)/deg)^T via MFMA ----------------
__global__ __launch_bounds__(256) void k2_u(const float* __restrict__ h,
                                            const unsigned short* __restrict__ WsTbf,
                                            const float* __restrict__ deg_part,
                                            float* __restrict__ deg,
                                            unsigned short* __restrict__ ubfT) {
    __shared__ float tile[64 * 65];
    __shared__ float sdeg[64];
    const int b    = blockIdx.y;
    const int m0   = blockIdx.x * 64;
    const int tid  = threadIdx.x;
    const int wave = tid >> 6, lane = tid & 63;
    const int ml = lane & 15, q = lane >> 4;
    const int row0 = wave * 16;

    // finalize deg for this block's 64 rows (each row finalized exactly once device-wide)
    if (tid < 64) {
        int j = m0 + tid;
        float s = 0.f;
        #pragma unroll
        for (int k = 0; k < 8; ++k) s += deg_part[(size_t)(b * 8 + k) * N_ + j];
        sdeg[tid] = s;
        deg[b * N_ + j] = s;
    }

    const float* A = h + (size_t)(b * N_ + m0 + row0 + ml) * F_ + q * 8;
    const unsigned short* Bb = WsTbf + ml * F_ + q * 8;

    f32x4 acc[4] = {};
    #pragma unroll
    for (int kk = 0; kk < F_; kk += 32) {
        float4 a0 = *reinterpret_cast<const float4*>(A + kk);
        float4 a1 = *reinterpret_cast<const float4*>(A + kk + 4);
        union { unsigned short s[8]; bf8_t v; } av;
        av.s[0] = f2bf(a0.x); av.s[1] = f2bf(a0.y); av.s[2] = f2bf(a0.z); av.s[3] = f2bf(a0.w);
        av.s[4] = f2bf(a1.x); av.s[5] = f2bf(a1.y); av.s[6] = f2bf(a1.z); av.s[7] = f2bf(a1.w);
        #pragma unroll
        for (int i = 0; i < 4; ++i) {
            bf8_t bv = *reinterpret_cast<const bf8_t*>(Bb + i * 16 * F_ + kk);
            acc[i] = __builtin_amdgcn_mfma_f32_16x16x32_bf16(av.v, bv, acc[i], 0, 0, 0);
        }
    }
    __syncthreads();   // sdeg ready; tile not yet written
    #pragma unroll
    for (int i = 0; i < 4; ++i) {
        int col = i * 16 + ml;
        #pragma unroll
        for (int r = 0; r < 4; ++r) {
            int rl = row0 + 4 * q + r;
            tile[rl * 65 + col] = acc[i][r] / sdeg[rl];
        }
    }
    __syncthreads();
    for (int jj = 0; jj < 16; ++jj) {
        int ll = wave + jj * 4;
        ubfT[(size_t)(b * L_ + ll) * N_ + m0 + lane] = f2bf(tile[lane * 65 + ll]);
    }
}

// ---------------- k3: h1 = ELU(g@u + b_s) via MFMA; fused tmu/tlv = (h1@Wmu|lv)/deg ----------------
__global__ __launch_bounds__(256) void k3_h1(const unsigned short* __restrict__ gbf,
                                             const unsigned short* __restrict__ ubfT,
                                             const float* __restrict__ b_s,
                                             const float* __restrict__ Wmu,
                                             const float* __restrict__ Wlv,
                                             const float* __restrict__ deg,
                                             unsigned short* __restrict__ h1q,
                                             float* __restrict__ tmu, float* __restrict__ tlv) {
    const int b    = blockIdx.y;
    const int tid  = threadIdx.x;
    const int wave = tid >> 6, lane = tid & 63;
    const int row0 = blockIdx.x * 64 + wave * 16;
    const int ml = lane & 15, q = lane >> 4;

    const unsigned short* A  = gbf  + (size_t)(b * N_ + row0 + ml) * N_ + q * 8;
    const unsigned short* B0 = ubfT + (size_t)(b * L_ + ml) * N_ + q * 8;

    f32x4 acc[4] = {};
    #pragma unroll 2
    for (int k = 0; k < N_; k += 32) {
        bf8_t a = *reinterpret_cast<const bf8_t*>(A + k);
        #pragma unroll
        for (int i = 0; i < 4; ++i) {
            bf8_t bb = *reinterpret_cast<const bf8_t*>(B0 + (size_t)i * 16 * N_ + k);
            acc[i] = __builtin_amdgcn_mfma_f32_16x16x32_bf16(a, bb, acc[i], 0, 0, 0);
        }
    }
    float bsv[4], wm[4], wl[4];
    #pragma unroll
    for (int i = 0; i < 4; ++i) {
        int col = i * 16 + ml;
        bsv[i] = b_s[col]; wm[i] = Wmu[col]; wl[i] = Wlv[col];
    }
    #pragma unroll
    for (int r = 0; r < 4; ++r) {
        int row = row0 + 4 * q + r;
        float pm = 0.f, pl = 0.f;
        #pragma unroll
        for (int i = 0; i < 4; ++i) {
            float hv = elu(acc[i][r] + bsv[i]);
            h1q[(size_t)(b * N_ + row) * L_ + i * 16 + ml] = f2bf(hv);
            pm = fmaf(hv, wm[i], pm);
            pl = fmaf(hv, wl[i], pl);
        }
        #pragma unroll
        for (int o = 1; o < 16; o <<= 1) { pm += __shfl_xor(pm, o); pl += __shfl_xor(pl, o); }
        if (ml == 0) {
            float idg = 1.f / deg[b * N_ + row];
            tmu[b * N_ + row] = pm * idg;
            tlv[b * N_ + row] = pl * idg;
        }
    }
}

// ---------------- k5: mu/lv -> z -> v, w = v/deg; per-block KL partial ----------------
__global__ __launch_bounds__(256) void k5_v(const unsigned short* __restrict__ gbf,
                                            const float* __restrict__ tmu, const float* __restrict__ tlv,
                                            const float* __restrict__ eps, const float* __restrict__ deg,
                                            const float* __restrict__ bmu, const float* __restrict__ blv,
                                            const float* __restrict__ beta,
                                            float* __restrict__ v, float* __restrict__ w,
                                            float* __restrict__ kl_part) {
    __shared__ float kls[4];
    const int b = blockIdx.y;
    const int wave = threadIdx.x >> 6, lane = threadIdx.x & 63;
    const int n0 = (blockIdx.x * 4 + wave) * 32;

    const float* tmr = tmu + b * N_ + lane * 8;
    const float* tlr = tlv + b * N_ + lane * 8;
    float tm[8], tl[8];
    *reinterpret_cast<float4*>(tm)     = *reinterpret_cast<const float4*>(tmr);
    *reinterpret_cast<float4*>(tm + 4) = *reinterpret_cast<const float4*>(tmr + 4);
    *reinterpret_cast<float4*>(tl)     = *reinterpret_cast<const float4*>(tlr);
    *reinterpret_cast<float4*>(tl + 4) = *reinterpret_cast<const float4*>(tlr + 4);

    const unsigned short* gbase = gbf + (size_t)(b * N_ + n0) * N_ + lane * 8;
    float myamu = 0.f, myalv = 0.f;
    #pragma unroll 4
    for (int r = 0; r < 32; ++r) {
        us8 gv = *reinterpret_cast<const us8*>(gbase + (size_t)r * N_);
        float amu = 0.f, alv = 0.f;
        #pragma unroll
        for (int j = 0; j < 8; ++j) {
            float gf = bf2f(gv[j]);
            amu = fmaf(gf, tm[j], amu);
            alv = fmaf(gf, tl[j], alv);
        }
        #pragma unroll
        for (int o = 32; o; o >>= 1) { amu += __shfl_xor(amu, o); alv += __shfl_xor(alv, o); }
        if (lane == r) { myamu = amu; myalv = alv; }
    }
    float klv = 0.f;
    if (lane < 32) {
        int n = n0 + lane;
        float mu = elu(myamu + bmu[0]);
        float lv = elu(myalv + blv[0]);
        float z  = mu + eps[b * N_ + n] * expf(0.5f * lv);
        float vv = 1.f / (1.f + expf(-beta[0] * z));
        v[b * N_ + n] = vv;
        w[b * N_ + n] = vv / deg[b * N_ + n];
        float e = expf(lv);
        klv = 1.f + 2.f * lv - mu * mu - e * e;
    }
    #pragma unroll
    for (int o = 32; o; o >>= 1) klv += __shfl_xor(klv, o);
    if (lane == 0) kls[wave] = klv;
    __syncthreads();
    if (threadIdx.x == 0)
        kl_part[blockIdx.y * 4 + blockIdx.x] = kls[0] + kls[1] + kls[2] + kls[3];
}

// ---------------- k6: p = g@w ; d = ELU(p*W_dec+b_dec); mse partial; hp partial ----------------
__global__ __launch_bounds__(256) void k6_dec(const unsigned short* __restrict__ gbf,
                                              const float* __restrict__ w, const float* __restrict__ v,
                                              const unsigned short* __restrict__ h1q,
                                              const float* __restrict__ Wdec, const float* __restrict__ bdec,
                                              float* __restrict__ hp_part, float* __restrict__ mse_part) {
    __shared__ float hps[4 * 64];
    __shared__ float mses[4];
    const int b = blockIdx.y;
    const int n0 = blockIdx.x * 64;
    const int tid = threadIdx.x, wave = tid >> 6, lane = tid & 63;
    const float wd = Wdec[lane], bd = bdec[lane];

    const float* wrow = w + b * N_ + lane * 8;
    float wr[8];
    *reinterpret_cast<float4*>(wr)     = *reinterpret_cast<const float4*>(wrow);
    *reinterpret_cast<float4*>(wr + 4) = *reinterpret_cast<const float4*>(wrow + 4);

    const unsigned short* gbase = gbf + (size_t)(b * N_ + n0 + wave * 16) * N_ + lane * 8;
    float hpl = 0.f, msep = 0.f;
    #pragma unroll 2
    for (int t = 0; t < 16; ++t) {
        int n = n0 + wave * 16 + t;
        us8 gv = *reinterpret_cast<const us8*>(gbase + (size_t)t * N_);
        float p = 0.f;
        #pragma unroll
        for (int j = 0; j < 8; ++j) p = fmaf(bf2f(gv[j]), wr[j], p);
        #pragma unroll
        for (int o = 32; o; o >>= 1) p += __shfl_xor(p, o);
        float dv = elu(p * wd + bd);
        float h1v = bf2f(h1q[(size_t)(b * N_ + n) * L_ + lane]);
        float diff = h1v - dv;
        msep = fmaf(diff, diff, msep);
        hpl  = fmaf(h1v, v[b * N_ + n], hpl);
    }
    hps[wave * 64 + lane] = hpl;
    #pragma unroll
    for (int o = 32; o; o >>= 1) msep += __shfl_xor(msep, o);
    if (lane == 0) mses[wave] = msep;
    __syncthreads();
    if (tid < 64) {
        float s = hps[tid] + hps[64 + tid] + hps[128 + tid] + hps[192 + tid];
        hp_part[(size_t)blockIdx.x * (B_ * 64) + b * 64 + tid] = s;
    }
    if (tid == 0)
        mse_part[blockIdx.y * 8 + blockIdx.x] = mses[0] + mses[1] + mses[2] + mses[3];
}

// ---------------- k7a: per-batch classifier head (128 parallel blocks) ----------------
__global__ __launch_bounds__(128) void k7a_head(const float* __restrict__ hp_part,
                                                const float* __restrict__ W1, const float* __restrict__ b1,
                                                const float* __restrict__ W2, const float* __restrict__ b2,
                                                const int* __restrict__ labels,
                                                float* __restrict__ lp, float* __restrict__ cor) {
    __shared__ float hps[64];
    __shared__ float acts[128];
    __shared__ float lgs[10];
    const int b = blockIdx.x, tid = threadIdx.x;
    if (tid < 64) {
        float s = 0.f;
        #pragma unroll
        for (int x = 0; x < 8; ++x) s += hp_part[(size_t)x * (B_ * 64) + b * 64 + tid];
        hps[tid] = s;
    }
    __syncthreads();
    float s0 = 0, s1 = 0, s2 = 0, s3 = 0;
    for (int l = 0; l < 64; l += 4) {
        s0 += hps[l]     * W1[(l)     * H_ + tid];
        s1 += hps[l + 1] * W1[(l + 1) * H_ + tid];
        s2 += hps[l + 2] * W1[(l + 2) * H_ + tid];
        s3 += hps[l + 3] * W1[(l + 3) * H_ + tid];
    }
    acts[tid] = elu((s0 + s1) + (s2 + s3) + b1[tid]);
    __syncthreads();
    if (tid < C_) {
        float lg = b2[tid];
        for (int hh = 0; hh < H_; ++hh) lg += acts[hh] * W2[hh * C_ + tid];
        lgs[tid] = lg;
    }
    __syncthreads();
    if (tid == 0) {
        float mx = lgs[0]; int am = 0;
        for (int c = 1; c < C_; ++c) if (lgs[c] > mx) { mx = lgs[c]; am = c; }
        float se = 0.f;
        for (int c = 0; c < C_; ++c) se += expf(lgs[c] - mx);
        int lbl = labels[b];
        lp[b]  = lgs[lbl] - mx - logf(se);
        cor[b] = (am == lbl) ? 1.f : 0.f;
    }
}

// ---------------- k7b: final reduce + loss ----------------
__global__ __launch_bounds__(128) void k7b_final(const float* __restrict__ lp, const float* __restrict__ cor,
                                                 const float* __restrict__ kl_part, const float* __restrict__ mse_part,
                                                 float* __restrict__ out) {
    __shared__ float r1[128], r2[128], r3[128], r4[128];
    int tid = threadIdx.x;
    r1[tid] = lp[tid]; r2[tid] = cor[tid];
    float k = 0.f, m = 0.f;
    #pragma unroll
    for (int i = 0; i < 4; ++i)  k += kl_part[tid + i * 128];
    #pragma unroll
    for (int i = 0; i < 8; ++i)  m += mse_part[tid + i * 128];
    r3[tid] = k; r4[tid] = m;
    __syncthreads();
    for (int o = 64; o; o >>= 1) {
        if (tid < o) { r1[tid] += r1[tid + o]; r2[tid] += r2[tid + o];
                       r3[tid] += r3[tid + o]; r4[tid] += r4[tid + o]; }
        __syncthreads();
    }
    if (tid == 0) {
        float nll = -r1[0] / (float)B_;
        float kl  = r3[0] * (-0.5f / (65536.f * 65536.f));   // (-0.5/M)*(sum/M), M = B*N
        float mse = r4[0] / (float)(B_ * N_ * L_);
        out[0] = nll + kl + mse;
        out[1] = r2[0] / (float)B_;
    }
}

extern "C" void kernel_launch(void* const* d_in, const int* in_sizes, int n_in,
                              void* d_out, int out_size, void* d_ws, size_t ws_size,
                              hipStream_t stream) {
    const float* g     = (const float*)d_in[0];
    const float* h     = (const float*)d_in[1];
    const int*   labels= (const int*)  d_in[2];
    const float* eps   = (const float*)d_in[3];
    const float* W_s   = (const float*)d_in[4];
    const float* b_s   = (const float*)d_in[5];
    const float* W_mu  = (const float*)d_in[6];
    const float* b_mu  = (const float*)d_in[7];
    const float* W_lv  = (const float*)d_in[8];
    const float* b_lv  = (const float*)d_in[9];
    const float* W_dec = (const float*)d_in[10];
    const float* b_dec = (const float*)d_in[11];
    const float* W1    = (const float*)d_in[12];
    const float* b1    = (const float*)d_in[13];
    const float* W2    = (const float*)d_in[14];
    const float* b2    = (const float*)d_in[15];
    const float* beta  = (const float*)d_in[16];

    float* ws = (float*)d_ws;
    float* deg_part = ws + OFF_DEGP;
    float* deg      = ws + OFF_DEG;
    float* hp_part  = ws + OFF_HPP;
    float* kl_part  = ws + OFF_KLP;
    float* mse_part = ws + OFF_MSEP;
    float* tmu      = ws + OFF_TMU;
    float* tlv      = ws + OFF_TLV;
    float* vv       = ws + OFF_V;
    float* wv       = ws + OFF_W;
    float* lp       = ws + OFF_LP;
    float* cor      = ws + OFF_COR;
    unsigned short* h1q   = (unsigned short*)(ws + OFF_H1Q);
    unsigned short* gbf   = (unsigned short*)(ws + OFF_GBF);
    unsigned short* ubfT  = (unsigned short*)(ws + OFF_UBFT);
    unsigned short* WsTbf = (unsigned short*)(ws + OFF_WSTBF);

    k1_deg  <<<dim3(4, B_), 256, 0, stream>>>(g, W_s, deg_part, gbf, WsTbf);
    k2_u    <<<dim3(8, B_), 256, 0, stream>>>(h, WsTbf, deg_part, deg, ubfT);
    k3_h1   <<<dim3(8, B_), 256, 0, stream>>>(gbf, ubfT, b_s, W_mu, W_lv, deg, h1q, tmu, tlv);
    k5_v    <<<dim3(4, B_), 256, 0, stream>>>(gbf, tmu, tlv, eps, deg, b_mu, b_lv, beta, vv, wv, kl_part);
    k6_dec  <<<dim3(8, B_), 256, 0, stream>>>(gbf, wv, vv, h1q, W_dec, b_dec, hp_part, mse_part);
    k7a_head<<<B_, 128, 0, stream>>>(hp_part, W1, b1, W2, b2, labels, lp, cor);
    k7b_final<<<1, 128, 0, stream>>>(lp, cor, kl_part, mse_part, (float*)d_out);
}